// Round 1
// baseline (6467.033 us; speedup 1.0000x reference)
//
#include <hip/hip_runtime.h>
#include <stdint.h>

#define NPTS 8192
#define NS   2048
#define KNNK 32

// ============================ FPS =============================
// One block per (b,t) frame. 1024 threads, 8 points each, dists in registers.
// Bit-exact vs reference: rn ops (no fma), sum order ((x+y)+z), argmax tie ->
// lowest index via value-match + atomicMin.
__global__ __launch_bounds__(1024)
void fps_kernel(const float* __restrict__ pts,
                float* __restrict__ anchors,
                float* __restrict__ out_xyz)
{
    const int bt  = blockIdx.x;        // b*4 + t0
    const int tid = threadIdx.x;
    const float* frame = pts + (size_t)bt * NPTS * 6;

    __shared__ float wmax[16];
    __shared__ unsigned int selIdx[2];
    __shared__ float selx, sely, selz;

    float px[8], py[8], pz[8], d[8];
#pragma unroll
    for (int j = 0; j < 8; ++j) {
        int n = j * 1024 + tid;
        px[j] = frame[n*6+0];
        py[j] = frame[n*6+1];
        pz[j] = frame[n*6+2];
        d[j]  = 3.4028234663852886e38f;
    }
    if (tid == 0) {
        selIdx[0] = 0xFFFFFFFFu;
        selIdx[1] = 0xFFFFFFFFu;
        selx = px[0]; sely = py[0]; selz = pz[0];
        float* aw = anchors + (size_t)bt * NS * 3;
        aw[0] = px[0]; aw[1] = py[0]; aw[2] = pz[0];
        float* ow = out_xyz + (size_t)bt * NS * 3;
        ow[0] = px[0]; ow[1] = py[0]; ow[2] = pz[0];
    }
    __syncthreads();
    float sx = selx, sy = sely, sz = selz;

    for (int i = 1; i < NS; ++i) {
        // update dists vs previous selection + per-thread max
        float mloc = 0.0f;
#pragma unroll
        for (int j = 0; j < 8; ++j) {
            float dx = __fsub_rn(px[j], sx);
            float dy = __fsub_rn(py[j], sy);
            float dz = __fsub_rn(pz[j], sz);
            float d2 = __fadd_rn(__fadd_rn(__fmul_rn(dx,dx), __fmul_rn(dy,dy)),
                                 __fmul_rn(dz,dz));
            d[j] = fminf(d[j], d2);
            mloc = fmaxf(mloc, d[j]);
        }
        // wave max
        float wm = mloc;
#pragma unroll
        for (int off = 1; off < 64; off <<= 1)
            wm = fmaxf(wm, __shfl_xor(wm, off, 64));
        if ((tid & 63) == 0) wmax[tid >> 6] = wm;
        __syncthreads();
        float M = wmax[0];
#pragma unroll
        for (int w = 1; w < 16; ++w) M = fmaxf(M, wmax[w]);
        // owner find: lowest global index achieving M (jnp.argmax tie rule)
        if (mloc == M) {
            unsigned best = 0xFFFFFFFFu;
#pragma unroll
            for (int j = 0; j < 8; ++j)
                if (d[j] == M) best = min(best, (unsigned)(j*1024 + tid));
            atomicMin(&selIdx[i & 1], best);
        }
        __syncthreads();
        unsigned sel = selIdx[i & 1];
        if ((sel & 1023u) == (unsigned)tid) {
            int jj = (int)(sel >> 10);
#pragma unroll
            for (int j = 0; j < 8; ++j)
                if (j == jj) { selx = px[j]; sely = py[j]; selz = pz[j]; }
        }
        if (tid == 0) selIdx[(i + 1) & 1] = 0xFFFFFFFFu;
        __syncthreads();
        sx = selx; sy = sely; sz = selz;
        if (tid == 0) {
            float* aw = anchors + ((size_t)bt * NS + i) * 3;
            aw[0] = sx; aw[1] = sy; aw[2] = sz;
            float* ow = out_xyz + ((size_t)bt * NS + i) * 3;
            ow[0] = sx; ow[1] = sy; ow[2] = sz;
        }
    }
}

// ============================ KNN =============================
// Thread = one anchor. 32-entry max-heap of packed (d2bits<<32|idx) u64 keys
// in LDS (interleaved -> 2-way bank alias = free). Strict-less insert +
// lexicographic eviction == jax.lax.top_k tie semantics (lowest index wins).
__global__ __launch_bounds__(128)
void knn_kernel(const float* __restrict__ pts,
                const float* __restrict__ anchors,
                unsigned short* __restrict__ knn_out)
{
    const int blk  = blockIdx.x;
    const int bt   = blk / 48;
    const int r    = blk % 48;
    const int di   = r / 16;       // 0,1,2 -> temporal offset -1,0,+1
    const int sblk = r % 16;
    const int b = bt >> 2, t0 = bt & 3;
    int lnb = t0 + di - 1; lnb = lnb < 0 ? 0 : (lnb > 3 ? 3 : lnb);
    const float* nb = pts + (size_t)(b*4 + lnb) * NPTS * 6;
    const int tid = threadIdx.x;
    const int s   = sblk * 128 + tid;

    const float* ap = anchors + ((size_t)bt * NS + s) * 3;
    float ax = ap[0], ay = ap[1], az = ap[2];

    __shared__ unsigned long long heap[32 * 128];  // 32 KB, interleaved
    __shared__ float4 tile[512];                   // 8 KB

#pragma unroll
    for (int i = 0; i < 32; ++i) heap[i*128 + tid] = ~0ull;
    unsigned long long rk = ~0ull;

    for (int tb = 0; tb < NPTS; tb += 512) {
        __syncthreads();
#pragma unroll
        for (int q = 0; q < 4; ++q) {
            int c = q * 128 + tid;
            int n = tb + c;
            tile[c] = make_float4(nb[n*6+0], nb[n*6+1], nb[n*6+2], 0.0f);
        }
        __syncthreads();
        for (int c = 0; c < 512; ++c) {
            float4 qv = tile[c];   // broadcast read
            float dx = __fsub_rn(ax, qv.x);
            float dy = __fsub_rn(ay, qv.y);
            float dz = __fsub_rn(az, qv.z);
            float d2 = __fadd_rn(__fadd_rn(__fmul_rn(dx,dx), __fmul_rn(dy,dy)),
                                 __fmul_rn(dz,dz));
            unsigned long long key =
                ((unsigned long long)__float_as_uint(d2) << 32) | (unsigned)(tb + c);
            if (key < rk) {
                unsigned long long cur = key;
                int n2 = 0;
                while (true) {
                    int c1 = 2*n2 + 1;
                    if (c1 >= 32) break;
                    unsigned long long k1 = heap[c1*128 + tid];
                    int big = c1; unsigned long long kb = k1;
                    if (c1 + 1 < 32) {
                        unsigned long long k2 = heap[(c1+1)*128 + tid];
                        if (k2 > k1) { big = c1+1; kb = k2; }
                    }
                    if (kb > cur) { heap[n2*128 + tid] = kb; n2 = big; }
                    else break;
                }
                heap[n2*128 + tid] = cur;
                rk = heap[tid];
            }
        }
    }
    unsigned short* op = knn_out + (((size_t)bt*3 + di) * NS + s) * KNNK;
#pragma unroll
    for (int i = 0; i < 32; ++i)
        op[i] = (unsigned short)(heap[i*128 + tid] & 0xFFFFFFFFull);
}

// ============================ MLP =============================
// Block = 2 anchors x 128 channels. h1 staged in LDS [2][64][36] (stride 36:
// bank-clean, 16B aligned rows for ds_read_b128 along k). WmT staged so lane
// reads are 2-way bank-aliased (free). relu/max commute: max then one relu.
__global__ __launch_bounds__(256)
void mlp_kernel(const float* __restrict__ pts,
                const float* __restrict__ anchors,
                const unsigned short* __restrict__ knn,
                const float* __restrict__ Wd,
                const float* __restrict__ Wm,
                float* __restrict__ out_feats)
{
    const int blk   = blockIdx.x;
    const int bt    = blk >> 10;
    const int spair = blk & 1023;
    const int b = bt >> 2, t0 = bt & 3;
    const int tid = threadIdx.x;
    const int a   = tid >> 7;      // local anchor 0/1
    const int p   = tid & 127;     // output channel
    const int s   = spair * 2 + a;

    __shared__ float WmT[64 * 128];      // 32 KB, [o][p]
    __shared__ float Wds[256];           // [o][c]
    __shared__ float h1[2][64][36];      // [a][o][k(pad 36)]
    __shared__ float d4s[2][32][4];

    for (int i = tid; i < 8192; i += 256) {
        int pp = i >> 6, oo = i & 63;
        WmT[oo * 128 + pp] = Wm[i];
    }
    Wds[tid & 255] = Wd[tid & 255];

    float fsum = 0.0f;

    for (int dd = 0; dd < 3; ++dd) {
        __syncthreads();   // protect h1/d4s reuse (and WmT/Wds on dd=0)
        if (tid < 64) {
            int sa = tid >> 5, k = tid & 31;
            int ss = spair * 2 + sa;
            int lnb = t0 + dd - 1; lnb = lnb < 0 ? 0 : (lnb > 3 ? 3 : lnb);
            const float* nbf = pts + (size_t)(b*4 + lnb) * NPTS * 6;
            const float* ap = anchors + ((size_t)bt * NS + ss) * 3;
            int idx = knn[(((size_t)bt*3 + dd) * NS + ss) * KNNK + k];
            d4s[sa][k][0] = nbf[idx*6+0] - ap[0];
            d4s[sa][k][1] = nbf[idx*6+1] - ap[1];
            d4s[sa][k][2] = nbf[idx*6+2] - ap[2];
            d4s[sa][k][3] = (float)(dd - 1);
        }
        __syncthreads();
        // h1: per anchor, 128 threads = (k 0..31) x (oq 0..3), 16 o's each
        {
            int k  = tid & 31;
            int oq = (tid >> 5) & 3;
            float4 dv = *(const float4*)&d4s[a][k][0];
#pragma unroll
            for (int ii = 0; ii < 16; ++ii) {
                int o = oq * 16 + ii;
                float4 w = *(const float4*)&Wds[o * 4];
                float h = fmaf(dv.x, w.x, fmaf(dv.y, w.y, fmaf(dv.z, w.z, dv.w * w.w)));
                h1[a][o][k] = fmaxf(h, 0.0f);
            }
        }
        __syncthreads();
        // h2: thread owns channel p; hoist Wm element over all 32 k
        float acc[32];
#pragma unroll
        for (int kk = 0; kk < 32; ++kk) acc[kk] = 0.0f;
        for (int o = 0; o < 64; ++o) {
            float wmv = WmT[o * 128 + p];
            const float4* hp = (const float4*)&h1[a][o][0];
#pragma unroll
            for (int kk = 0; kk < 8; ++kk) {
                float4 hv = hp[kk];   // broadcast ds_read_b128
                acc[kk*4+0] = fmaf(wmv, hv.x, acc[kk*4+0]);
                acc[kk*4+1] = fmaf(wmv, hv.y, acc[kk*4+1]);
                acc[kk*4+2] = fmaf(wmv, hv.z, acc[kk*4+2]);
                acc[kk*4+3] = fmaf(wmv, hv.w, acc[kk*4+3]);
            }
        }
        float mx = acc[0];
#pragma unroll
        for (int kk = 1; kk < 32; ++kk) mx = fmaxf(mx, acc[kk]);
        fsum += fmaxf(mx, 0.0f);   // max_k relu(x) == relu(max_k x)
    }
    out_feats[((size_t)bt * 128 + p) * NS + s] = fsum;
}

// ========================== launcher ==========================
extern "C" void kernel_launch(void* const* d_in, const int* in_sizes, int n_in,
                              void* d_out, int out_size, void* d_ws, size_t ws_size,
                              hipStream_t stream)
{
    const float* pts = (const float*)d_in[0];   // [2,4,8192,6]
    const float* Wd  = (const float*)d_in[1];   // [64,4]
    const float* Wm  = (const float*)d_in[2];   // [128,64]

    float* out_xyz   = (float*)d_out;                 // [2,4,2048,3]
    float* out_feats = out_xyz + 8 * NS * 3;          // [2,4,128,2048]

    float* anchors      = (float*)d_ws;                                   // 8*2048*3 f32
    unsigned short* knn = (unsigned short*)((char*)d_ws +
                          (size_t)8 * NS * 3 * sizeof(float));            // 8*3*2048*32 u16

    fps_kernel<<<8, 1024, 0, stream>>>(pts, anchors, out_xyz);
    knn_kernel<<<8 * 3 * 16, 128, 0, stream>>>(pts, anchors, knn);
    mlp_kernel<<<8 * (NS / 2), 256, 0, stream>>>(pts, anchors, knn, Wd, Wm, out_feats);
}

// Round 2
// 3977.181 us; speedup vs baseline: 1.6260x; 1.6260x over previous
//
#include <hip/hip_runtime.h>
#include <stdint.h>

#define NPTS 8192
#define NS   2048
#define KNNK 32

typedef unsigned long long u64;

// ============================ FPS =============================
// One block per (b,t) frame. 1024 threads, 8 points each, dists in registers.
// Bit-exact vs reference: rn ops (no fma), sum order ((x+y)+z), argmax tie ->
// lowest index via value-match + atomicMin.
__global__ __launch_bounds__(1024)
void fps_kernel(const float* __restrict__ pts,
                float* __restrict__ anchors,
                float* __restrict__ out_xyz)
{
    const int bt  = blockIdx.x;        // b*4 + t0
    const int tid = threadIdx.x;
    const float* frame = pts + (size_t)bt * NPTS * 6;

    __shared__ float wmax[16];
    __shared__ unsigned int selIdx[2];
    __shared__ float selx, sely, selz;

    float px[8], py[8], pz[8], d[8];
#pragma unroll
    for (int j = 0; j < 8; ++j) {
        int n = j * 1024 + tid;
        px[j] = frame[n*6+0];
        py[j] = frame[n*6+1];
        pz[j] = frame[n*6+2];
        d[j]  = 3.4028234663852886e38f;
    }
    if (tid == 0) {
        selIdx[0] = 0xFFFFFFFFu;
        selIdx[1] = 0xFFFFFFFFu;
        selx = px[0]; sely = py[0]; selz = pz[0];
        float* aw = anchors + (size_t)bt * NS * 3;
        aw[0] = px[0]; aw[1] = py[0]; aw[2] = pz[0];
        float* ow = out_xyz + (size_t)bt * NS * 3;
        ow[0] = px[0]; ow[1] = py[0]; ow[2] = pz[0];
    }
    __syncthreads();
    float sx = selx, sy = sely, sz = selz;

    for (int i = 1; i < NS; ++i) {
        // update dists vs previous selection + per-thread max
        float mloc = 0.0f;
#pragma unroll
        for (int j = 0; j < 8; ++j) {
            float dx = __fsub_rn(px[j], sx);
            float dy = __fsub_rn(py[j], sy);
            float dz = __fsub_rn(pz[j], sz);
            float d2 = __fadd_rn(__fadd_rn(__fmul_rn(dx,dx), __fmul_rn(dy,dy)),
                                 __fmul_rn(dz,dz));
            d[j] = fminf(d[j], d2);
            mloc = fmaxf(mloc, d[j]);
        }
        // wave max
        float wm = mloc;
#pragma unroll
        for (int off = 1; off < 64; off <<= 1)
            wm = fmaxf(wm, __shfl_xor(wm, off, 64));
        if ((tid & 63) == 0) wmax[tid >> 6] = wm;
        __syncthreads();
        float M = wmax[0];
#pragma unroll
        for (int w = 1; w < 16; ++w) M = fmaxf(M, wmax[w]);
        // owner find: lowest global index achieving M (jnp.argmax tie rule)
        if (mloc == M) {
            unsigned best = 0xFFFFFFFFu;
#pragma unroll
            for (int j = 0; j < 8; ++j)
                if (d[j] == M) best = min(best, (unsigned)(j*1024 + tid));
            atomicMin(&selIdx[i & 1], best);
        }
        __syncthreads();
        unsigned sel = selIdx[i & 1];
        if ((sel & 1023u) == (unsigned)tid) {
            int jj = (int)(sel >> 10);
#pragma unroll
            for (int j = 0; j < 8; ++j)
                if (j == jj) { selx = px[j]; sely = py[j]; selz = pz[j]; }
        }
        if (tid == 0) selIdx[(i + 1) & 1] = 0xFFFFFFFFu;
        __syncthreads();
        sx = selx; sy = sely; sz = selz;
        if (tid == 0) {
            float* aw = anchors + ((size_t)bt * NS + i) * 3;
            aw[0] = sx; aw[1] = sy; aw[2] = sz;
            float* ow = out_xyz + ((size_t)bt * NS + i) * 3;
            ow[0] = sx; ow[1] = sy; ow[2] = sz;
        }
    }
}

// ============================ KNN =============================
// 1 wave (64 threads) per block, one anchor per lane. Per lane, in LDS
// columns (interleaved, stride 64 u64s): rows 0..31 = sorted main top-32,
// rows 32..63 = append buffer, row 64 = trash. Fast path is branchless:
// key = (d2bits<<32|idx); if key<rk append (losers write to trash row).
// Compaction (wave-uniform, lane-parallel): bitonic-sort buffer, one
// bitonic merge pass vs main keeping mins, 5 passes to re-sort, rk refresh.
// Exactness: rk lags (lazy), but key>=rk implies >=32 compacted keys are
// smaller -> safe to drop. Set/tie semantics identical to jax top_k
// (lexicographic (d2,idx)); downstream max-pool is order-insensitive.
__device__ __forceinline__ void knn_compact(u64* st, int lane, int& cnt, u64& rk)
{
    // pad unused buffer slots with +inf keys
    for (int e = 0; e < 32; ++e)
        if (e >= cnt) st[(e + 32) * 64 + lane] = ~0ull;
    // bitonic sort rows 32..63 ascending (per-lane column, uniform flow)
    for (int k = 2; k <= 32; k <<= 1)
        for (int j = k >> 1; j > 0; j >>= 1)
            for (int i = 0; i < 32; ++i) {
                int l = i ^ j;
                if (l > i) {
                    u64 a = st[(i + 32) * 64 + lane];
                    u64 b = st[(l + 32) * 64 + lane];
                    bool asc = ((i & k) == 0);
                    if ((a > b) == asc) {
                        st[(i + 32) * 64 + lane] = b;
                        st[(l + 32) * 64 + lane] = a;
                    }
                }
            }
    // merge step: main[i] vs buf[31-i] (asc+asc viewed as bitonic);
    // keep the 32 smallest in main (now a bitonic sequence)
    for (int i = 0; i < 32; ++i) {
        u64 a = st[i * 64 + lane];
        u64 b = st[(63 - i) * 64 + lane];
        if (b < a) st[i * 64 + lane] = b;
    }
    // sort the bitonic main ascending: 5 merge passes
    for (int j = 16; j > 0; j >>= 1)
        for (int i = 0; i < 32; ++i) {
            int l = i ^ j;
            if (l > i) {
                u64 a = st[i * 64 + lane];
                u64 b = st[l * 64 + lane];
                if (a > b) {
                    st[i * 64 + lane] = b;
                    st[l * 64 + lane] = a;
                }
            }
        }
    rk = st[31 * 64 + lane];
    cnt = 0;
}

__global__ __launch_bounds__(64)
void knn_kernel(const float* __restrict__ pts,
                const float* __restrict__ anchors,
                unsigned short* __restrict__ knn_out)
{
    const int blk  = blockIdx.x;       // 8bt * 3di * 32 sblk
    const int bt   = blk / 96;
    const int r    = blk % 96;
    const int di   = r / 32;           // temporal offset index 0,1,2
    const int sblk = r % 32;
    const int b = bt >> 2, t0 = bt & 3;
    int lnb = t0 + di - 1; lnb = lnb < 0 ? 0 : (lnb > 3 ? 3 : lnb);
    const float* nb = pts + (size_t)(b * 4 + lnb) * NPTS * 6;
    const int lane = threadIdx.x;
    const int s    = sblk * 64 + lane;

    const float* ap = anchors + ((size_t)bt * NS + s) * 3;
    float ax = ap[0], ay = ap[1], az = ap[2];

    __shared__ u64 st[65 * 64];        // 33.25 KB
    __shared__ float4 tile[512];       // 8 KB

    for (int e = 0; e < 64; ++e) st[e * 64 + lane] = ~0ull;
    u64 rk = ~0ull;
    int cnt = 0;

    for (int tb = 0; tb < NPTS; tb += 512) {
        __syncthreads();
#pragma unroll
        for (int q = 0; q < 8; ++q) {
            int c = q * 64 + lane;
            int n = tb + c;
            tile[c] = make_float4(nb[n*6+0], nb[n*6+1], nb[n*6+2], 0.0f);
        }
        __syncthreads();
        for (int c0 = 0; c0 < 512; c0 += 8) {
#pragma unroll
            for (int j = 0; j < 8; ++j) {
                float4 qv = tile[c0 + j];          // broadcast ds_read_b128
                float dx = __fsub_rn(ax, qv.x);
                float dy = __fsub_rn(ay, qv.y);
                float dz = __fsub_rn(az, qv.z);
                float d2 = __fadd_rn(__fadd_rn(__fmul_rn(dx,dx), __fmul_rn(dy,dy)),
                                     __fmul_rn(dz,dz));
                u64 key = ((u64)__float_as_uint(d2) << 32)
                        | (unsigned)(tb + c0 + j);
                bool p = key < rk;
                int row = p ? (32 + cnt) : 64;     // losers -> trash row
                st[row * 64 + lane] = key;
                cnt += p ? 1 : 0;
            }
            // pre-batch cnt <= 23 always, so post-batch cnt <= 31 <= capacity
            if (__any(cnt >= 24)) knn_compact(st, lane, cnt, rk);
        }
    }
    knn_compact(st, lane, cnt, rk);

    unsigned short* op = knn_out + (((size_t)bt * 3 + di) * NS + s) * KNNK;
#pragma unroll
    for (int e = 0; e < 32; ++e)
        op[e] = (unsigned short)(st[e * 64 + lane] & 0xFFFFull);
}

// ============================ MLP =============================
// Block = 2 anchors x 128 channels. h1 staged in LDS [2][64][36] (stride 36:
// bank-clean, 16B aligned rows for ds_read_b128 along k). WmT staged so lane
// reads are 2-way bank-aliased (free). relu/max commute: max then one relu.
__global__ __launch_bounds__(256)
void mlp_kernel(const float* __restrict__ pts,
                const float* __restrict__ anchors,
                const unsigned short* __restrict__ knn,
                const float* __restrict__ Wd,
                const float* __restrict__ Wm,
                float* __restrict__ out_feats)
{
    const int blk   = blockIdx.x;
    const int bt    = blk >> 10;
    const int spair = blk & 1023;
    const int b = bt >> 2, t0 = bt & 3;
    const int tid = threadIdx.x;
    const int a   = tid >> 7;      // local anchor 0/1
    const int p   = tid & 127;     // output channel
    const int s   = spair * 2 + a;

    __shared__ float WmT[64 * 128];      // 32 KB, [o][p]
    __shared__ float Wds[256];           // [o][c]
    __shared__ float h1[2][64][36];      // [a][o][k(pad 36)]
    __shared__ float d4s[2][32][4];

    for (int i = tid; i < 8192; i += 256) {
        int pp = i >> 6, oo = i & 63;
        WmT[oo * 128 + pp] = Wm[i];
    }
    Wds[tid & 255] = Wd[tid & 255];

    float fsum = 0.0f;

    for (int dd = 0; dd < 3; ++dd) {
        __syncthreads();   // protect h1/d4s reuse (and WmT/Wds on dd=0)
        if (tid < 64) {
            int sa = tid >> 5, k = tid & 31;
            int ss = spair * 2 + sa;
            int lnb = t0 + dd - 1; lnb = lnb < 0 ? 0 : (lnb > 3 ? 3 : lnb);
            const float* nbf = pts + (size_t)(b*4 + lnb) * NPTS * 6;
            const float* ap = anchors + ((size_t)bt * NS + ss) * 3;
            int idx = knn[(((size_t)bt*3 + dd) * NS + ss) * KNNK + k];
            d4s[sa][k][0] = nbf[idx*6+0] - ap[0];
            d4s[sa][k][1] = nbf[idx*6+1] - ap[1];
            d4s[sa][k][2] = nbf[idx*6+2] - ap[2];
            d4s[sa][k][3] = (float)(dd - 1);
        }
        __syncthreads();
        // h1: per anchor, 128 threads = (k 0..31) x (oq 0..3), 16 o's each
        {
            int k  = tid & 31;
            int oq = (tid >> 5) & 3;
            float4 dv = *(const float4*)&d4s[a][k][0];
#pragma unroll
            for (int ii = 0; ii < 16; ++ii) {
                int o = oq * 16 + ii;
                float4 w = *(const float4*)&Wds[o * 4];
                float h = fmaf(dv.x, w.x, fmaf(dv.y, w.y, fmaf(dv.z, w.z, dv.w * w.w)));
                h1[a][o][k] = fmaxf(h, 0.0f);
            }
        }
        __syncthreads();
        // h2: thread owns channel p; hoist Wm element over all 32 k
        float acc[32];
#pragma unroll
        for (int kk = 0; kk < 32; ++kk) acc[kk] = 0.0f;
        for (int o = 0; o < 64; ++o) {
            float wmv = WmT[o * 128 + p];
            const float4* hp = (const float4*)&h1[a][o][0];
#pragma unroll
            for (int kk = 0; kk < 8; ++kk) {
                float4 hv = hp[kk];   // broadcast ds_read_b128
                acc[kk*4+0] = fmaf(wmv, hv.x, acc[kk*4+0]);
                acc[kk*4+1] = fmaf(wmv, hv.y, acc[kk*4+1]);
                acc[kk*4+2] = fmaf(wmv, hv.z, acc[kk*4+2]);
                acc[kk*4+3] = fmaf(wmv, hv.w, acc[kk*4+3]);
            }
        }
        float mx = acc[0];
#pragma unroll
        for (int kk = 1; kk < 32; ++kk) mx = fmaxf(mx, acc[kk]);
        fsum += fmaxf(mx, 0.0f);   // max_k relu(x) == relu(max_k x)
    }
    out_feats[((size_t)bt * 128 + p) * NS + s] = fsum;
}

// ========================== launcher ==========================
extern "C" void kernel_launch(void* const* d_in, const int* in_sizes, int n_in,
                              void* d_out, int out_size, void* d_ws, size_t ws_size,
                              hipStream_t stream)
{
    const float* pts = (const float*)d_in[0];   // [2,4,8192,6]
    const float* Wd  = (const float*)d_in[1];   // [64,4]
    const float* Wm  = (const float*)d_in[2];   // [128,64]

    float* out_xyz   = (float*)d_out;                 // [2,4,2048,3]
    float* out_feats = out_xyz + 8 * NS * 3;          // [2,4,128,2048]

    float* anchors      = (float*)d_ws;                                   // 8*2048*3 f32
    unsigned short* knn = (unsigned short*)((char*)d_ws +
                          (size_t)8 * NS * 3 * sizeof(float));            // 8*3*2048*32 u16

    fps_kernel<<<8, 1024, 0, stream>>>(pts, anchors, out_xyz);
    knn_kernel<<<8 * 3 * 32, 64, 0, stream>>>(pts, anchors, knn);
    mlp_kernel<<<8 * (NS / 2), 256, 0, stream>>>(pts, anchors, knn, Wd, Wm, out_feats);
}

// Round 3
// 3498.395 us; speedup vs baseline: 1.8486x; 1.1369x over previous
//
#include <hip/hip_runtime.h>
#include <stdint.h>

#define NPTS 8192
#define NS   2048
#define KNNK 32

typedef unsigned long long u64;

// ============================ FPS =============================
// One block per (b,t) frame, 512 threads (8 waves), 16 points/thread in
// registers. ONE barrier per iteration:
//   key = (d2bits<<32)|(8191-idx)  -> u64 atomicMax == argmax w/ lowest-index
//   tie-break (d2>=0 so float bits are order-monotone; jnp.argmax semantics).
//   3-deep ring of result slots: slot (i+1)%3 is reset at iter i, read at
//   iter i+2 -> reset/read separated by barrier i+1 (race-free, 1 barrier).
//   Coords fetched by ALL threads from LDS float4 copy (broadcast read).
// Exact math: rn ops (no fma contraction), sum order ((x+y)+z).
__global__ __launch_bounds__(512)
void fps_kernel(const float* __restrict__ pts,
                float* __restrict__ out_xyz)
{
    const int bt  = blockIdx.x;        // b*4 + t0
    const int tid = threadIdx.x;
    const float* frame = pts + (size_t)bt * NPTS * 6;

    __shared__ float4 p4[NPTS];        // 128 KB coords copy
    __shared__ u64 ring[3];

    float px[16], py[16], pz[16], d[16];
#pragma unroll
    for (int j = 0; j < 16; ++j) {
        int n = j * 512 + tid;
        float x = frame[n*6+0], y = frame[n*6+1], z = frame[n*6+2];
        px[j] = x; py[j] = y; pz[j] = z;
        d[j]  = 3.4028234663852886e38f;
        p4[n] = make_float4(x, y, z, 0.0f);
    }
    if (tid < 3) ring[tid] = 0;
    if (tid == 0) {                    // selection 0 = point 0
        float* ow = out_xyz + (size_t)bt * NS * 3;
        ow[0] = px[0]; ow[1] = py[0]; ow[2] = pz[0];
    }
    __syncthreads();
    float sx = p4[0].x, sy = p4[0].y, sz = p4[0].z;

    int r = 1;                         // ring slot for iteration i
    for (int i = 1; i < NS; ++i) {
        // update dists vs previous selection, track local max
        float mloc = 0.0f;
#pragma unroll
        for (int j = 0; j < 16; ++j) {
            float dx = __fsub_rn(px[j], sx);
            float dy = __fsub_rn(py[j], sy);
            float dz = __fsub_rn(pz[j], sz);
            float d2 = __fadd_rn(__fadd_rn(__fmul_rn(dx,dx), __fmul_rn(dy,dy)),
                                 __fmul_rn(dz,dz));
            float nd = fminf(d[j], d2);
            d[j] = nd;
            mloc = fmaxf(mloc, nd);
        }
        // lowest local index holding mloc (descending pass -> first match)
        int bestn = 0;
#pragma unroll
        for (int j = 15; j >= 0; --j)
            bestn = (d[j] == mloc) ? (j * 512 + tid) : bestn;
        u64 key = ((u64)__float_as_uint(mloc) << 32) | (unsigned)(8191 - bestn);
        // wave reduce (max key)
#pragma unroll
        for (int off = 32; off > 0; off >>= 1) {
            u64 o = __shfl_xor(key, off, 64);
            key = (o > key) ? o : key;
        }
        if ((tid & 63) == 0) atomicMax(&ring[r], key);
        int rn = r + 1; if (rn == 3) rn = 0;
        if (tid == 0) ring[rn] = 0;    // reset future slot (read 2 iters away)
        __syncthreads();
        u64 k = ring[r];
        int idx = 8191 - (int)(k & 0xFFFFFFFFu);
        float4 c = p4[idx];            // broadcast ds_read_b128
        sx = c.x; sy = c.y; sz = c.z;
        if (tid == 0) {
            float* ow = out_xyz + ((size_t)bt * NS + i) * 3;
            ow[0] = sx; ow[1] = sy; ow[2] = sz;
        }
        r = rn;
    }
}

// ============================ KNN =============================
// 1 wave (64 threads) per block, one anchor per lane. Per lane, in LDS
// columns (interleaved, stride 64 u64s): rows 0..31 = sorted main top-32,
// rows 32..63 = append buffer, row 64 = trash. Fast path is branchless:
// key = (d2bits<<32|idx); if key<rk append (losers write to trash row).
// Compaction (wave-uniform, lane-parallel): bitonic-sort buffer, one
// bitonic merge pass vs main keeping mins, 5 passes to re-sort, rk refresh.
// Exactness: rk lags (lazy), but key>=rk implies >=32 compacted keys are
// smaller -> safe to drop. Set/tie semantics identical to jax top_k
// (lexicographic (d2,idx)); downstream max-pool is order-insensitive.
__device__ __forceinline__ void knn_compact(u64* st, int lane, int& cnt, u64& rk)
{
    for (int e = 0; e < 32; ++e)
        if (e >= cnt) st[(e + 32) * 64 + lane] = ~0ull;
    for (int k = 2; k <= 32; k <<= 1)
        for (int j = k >> 1; j > 0; j >>= 1)
            for (int i = 0; i < 32; ++i) {
                int l = i ^ j;
                if (l > i) {
                    u64 a = st[(i + 32) * 64 + lane];
                    u64 b = st[(l + 32) * 64 + lane];
                    bool asc = ((i & k) == 0);
                    if ((a > b) == asc) {
                        st[(i + 32) * 64 + lane] = b;
                        st[(l + 32) * 64 + lane] = a;
                    }
                }
            }
    for (int i = 0; i < 32; ++i) {
        u64 a = st[i * 64 + lane];
        u64 b = st[(63 - i) * 64 + lane];
        if (b < a) st[i * 64 + lane] = b;
    }
    for (int j = 16; j > 0; j >>= 1)
        for (int i = 0; i < 32; ++i) {
            int l = i ^ j;
            if (l > i) {
                u64 a = st[i * 64 + lane];
                u64 b = st[l * 64 + lane];
                if (a > b) {
                    st[i * 64 + lane] = b;
                    st[l * 64 + lane] = a;
                }
            }
        }
    rk = st[31 * 64 + lane];
    cnt = 0;
}

__global__ __launch_bounds__(64)
void knn_kernel(const float* __restrict__ pts,
                const float* __restrict__ anchors,
                unsigned short* __restrict__ knn_out)
{
    const int blk  = blockIdx.x;       // 8bt * 3di * 32 sblk
    const int bt   = blk / 96;
    const int r    = blk % 96;
    const int di   = r / 32;
    const int sblk = r % 32;
    const int b = bt >> 2, t0 = bt & 3;
    int lnb = t0 + di - 1; lnb = lnb < 0 ? 0 : (lnb > 3 ? 3 : lnb);
    const float* nb = pts + (size_t)(b * 4 + lnb) * NPTS * 6;
    const int lane = threadIdx.x;
    const int s    = sblk * 64 + lane;

    const float* ap = anchors + ((size_t)bt * NS + s) * 3;
    float ax = ap[0], ay = ap[1], az = ap[2];

    __shared__ u64 st[65 * 64];        // 33.25 KB
    __shared__ float4 tile[512];       // 8 KB

    for (int e = 0; e < 64; ++e) st[e * 64 + lane] = ~0ull;
    u64 rk = ~0ull;
    int cnt = 0;

    for (int tb = 0; tb < NPTS; tb += 512) {
        __syncthreads();
#pragma unroll
        for (int q = 0; q < 8; ++q) {
            int c = q * 64 + lane;
            int n = tb + c;
            tile[c] = make_float4(nb[n*6+0], nb[n*6+1], nb[n*6+2], 0.0f);
        }
        __syncthreads();
        for (int c0 = 0; c0 < 512; c0 += 8) {
#pragma unroll
            for (int j = 0; j < 8; ++j) {
                float4 qv = tile[c0 + j];
                float dx = __fsub_rn(ax, qv.x);
                float dy = __fsub_rn(ay, qv.y);
                float dz = __fsub_rn(az, qv.z);
                float d2 = __fadd_rn(__fadd_rn(__fmul_rn(dx,dx), __fmul_rn(dy,dy)),
                                     __fmul_rn(dz,dz));
                u64 key = ((u64)__float_as_uint(d2) << 32)
                        | (unsigned)(tb + c0 + j);
                bool p = key < rk;
                int row = p ? (32 + cnt) : 64;
                st[row * 64 + lane] = key;
                cnt += p ? 1 : 0;
            }
            if (__any(cnt >= 24)) knn_compact(st, lane, cnt, rk);
        }
    }
    knn_compact(st, lane, cnt, rk);

    unsigned short* op = knn_out + (((size_t)bt * 3 + di) * NS + s) * KNNK;
#pragma unroll
    for (int e = 0; e < 32; ++e)
        op[e] = (unsigned short)(st[e * 64 + lane] & 0xFFFFull);
}

// ============================ MLP =============================
// Block = 2 anchors x 128 channels. h1 staged in LDS [2][64][36] (stride 36:
// bank-clean, 16B aligned rows for ds_read_b128 along k). relu/max commute.
__global__ __launch_bounds__(256)
void mlp_kernel(const float* __restrict__ pts,
                const float* __restrict__ anchors,
                const unsigned short* __restrict__ knn,
                const float* __restrict__ Wd,
                const float* __restrict__ Wm,
                float* __restrict__ out_feats)
{
    const int blk   = blockIdx.x;
    const int bt    = blk >> 10;
    const int spair = blk & 1023;
    const int b = bt >> 2, t0 = bt & 3;
    const int tid = threadIdx.x;
    const int a   = tid >> 7;
    const int p   = tid & 127;
    const int s   = spair * 2 + a;

    __shared__ float WmT[64 * 128];
    __shared__ float Wds[256];
    __shared__ float h1[2][64][36];
    __shared__ float d4s[2][32][4];

    for (int i = tid; i < 8192; i += 256) {
        int pp = i >> 6, oo = i & 63;
        WmT[oo * 128 + pp] = Wm[i];
    }
    Wds[tid & 255] = Wd[tid & 255];

    float fsum = 0.0f;

    for (int dd = 0; dd < 3; ++dd) {
        __syncthreads();
        if (tid < 64) {
            int sa = tid >> 5, k = tid & 31;
            int ss = spair * 2 + sa;
            int lnb = t0 + dd - 1; lnb = lnb < 0 ? 0 : (lnb > 3 ? 3 : lnb);
            const float* nbf = pts + (size_t)(b*4 + lnb) * NPTS * 6;
            const float* ap = anchors + ((size_t)bt * NS + ss) * 3;
            int idx = knn[(((size_t)bt*3 + dd) * NS + ss) * KNNK + k];
            d4s[sa][k][0] = nbf[idx*6+0] - ap[0];
            d4s[sa][k][1] = nbf[idx*6+1] - ap[1];
            d4s[sa][k][2] = nbf[idx*6+2] - ap[2];
            d4s[sa][k][3] = (float)(dd - 1);
        }
        __syncthreads();
        {
            int k  = tid & 31;
            int oq = (tid >> 5) & 3;
            float4 dv = *(const float4*)&d4s[a][k][0];
#pragma unroll
            for (int ii = 0; ii < 16; ++ii) {
                int o = oq * 16 + ii;
                float4 w = *(const float4*)&Wds[o * 4];
                float h = fmaf(dv.x, w.x, fmaf(dv.y, w.y, fmaf(dv.z, w.z, dv.w * w.w)));
                h1[a][o][k] = fmaxf(h, 0.0f);
            }
        }
        __syncthreads();
        float acc[32];
#pragma unroll
        for (int kk = 0; kk < 32; ++kk) acc[kk] = 0.0f;
        for (int o = 0; o < 64; ++o) {
            float wmv = WmT[o * 128 + p];
            const float4* hp = (const float4*)&h1[a][o][0];
#pragma unroll
            for (int kk = 0; kk < 8; ++kk) {
                float4 hv = hp[kk];
                acc[kk*4+0] = fmaf(wmv, hv.x, acc[kk*4+0]);
                acc[kk*4+1] = fmaf(wmv, hv.y, acc[kk*4+1]);
                acc[kk*4+2] = fmaf(wmv, hv.z, acc[kk*4+2]);
                acc[kk*4+3] = fmaf(wmv, hv.w, acc[kk*4+3]);
            }
        }
        float mx = acc[0];
#pragma unroll
        for (int kk = 1; kk < 32; ++kk) mx = fmaxf(mx, acc[kk]);
        fsum += fmaxf(mx, 0.0f);
    }
    out_feats[((size_t)bt * 128 + p) * NS + s] = fsum;
}

// ========================== launcher ==========================
extern "C" void kernel_launch(void* const* d_in, const int* in_sizes, int n_in,
                              void* d_out, int out_size, void* d_ws, size_t ws_size,
                              hipStream_t stream)
{
    const float* pts = (const float*)d_in[0];   // [2,4,8192,6]
    const float* Wd  = (const float*)d_in[1];   // [64,4]
    const float* Wm  = (const float*)d_in[2];   // [128,64]

    float* out_xyz   = (float*)d_out;                 // [2,4,2048,3] == anchors
    float* out_feats = out_xyz + 8 * NS * 3;          // [2,4,128,2048]

    unsigned short* knn = (unsigned short*)d_ws;      // 8*3*2048*32 u16

    fps_kernel<<<8, 512, 0, stream>>>(pts, out_xyz);
    knn_kernel<<<8 * 3 * 32, 64, 0, stream>>>(pts, out_xyz, knn);
    mlp_kernel<<<8 * (NS / 2), 256, 0, stream>>>(pts, out_xyz, knn, Wd, Wm, out_feats);
}

// Round 4
// 2983.030 us; speedup vs baseline: 2.1679x; 1.1728x over previous
//
#include <hip/hip_runtime.h>
#include <stdint.h>

#define NPTS 8192
#define NS   2048
#define KNNK 32

typedef unsigned long long u64;
typedef float f32x2 __attribute__((ext_vector_type(2)));

// DPP-based 64-lane reduces. CDNA keeps gfx9 DPP ctrls:
// quad_perm xor1=0xB1, xor2=0x4E, ROW_HALF_MIRROR=0x141 (lane^7),
// ROW_MIRROR=0x140 (lane^15), ROW_BCAST15=0x142, ROW_BCAST31=0x143.
// After the 6 steps lanes 48..63 hold the full 64-lane result; readlane 63.
__device__ __forceinline__ float wave_max_f32_dpp(float x) {
    int t;
    t = __builtin_amdgcn_update_dpp(0, __float_as_int(x), 0xB1, 0xF, 0xF, false);
    x = fmaxf(x, __int_as_float(t));
    t = __builtin_amdgcn_update_dpp(0, __float_as_int(x), 0x4E, 0xF, 0xF, false);
    x = fmaxf(x, __int_as_float(t));
    t = __builtin_amdgcn_update_dpp(0, __float_as_int(x), 0x141, 0xF, 0xF, false);
    x = fmaxf(x, __int_as_float(t));
    t = __builtin_amdgcn_update_dpp(0, __float_as_int(x), 0x140, 0xF, 0xF, false);
    x = fmaxf(x, __int_as_float(t));
    // bcast steps: non-written lanes keep old=0; d2>=0 so max(x,0)=x is a no-op
    t = __builtin_amdgcn_update_dpp(0, __float_as_int(x), 0x142, 0xF, 0xF, false);
    x = fmaxf(x, __int_as_float(t));
    t = __builtin_amdgcn_update_dpp(0, __float_as_int(x), 0x143, 0xF, 0xF, false);
    x = fmaxf(x, __int_as_float(t));
    return x;
}

__device__ __forceinline__ int wave_min_i32_dpp(int x) {
    const int INF = 0x7FFFFFFF;
    int t;
    t = __builtin_amdgcn_update_dpp(INF, x, 0xB1, 0xF, 0xF, false);
    x = t < x ? t : x;
    t = __builtin_amdgcn_update_dpp(INF, x, 0x4E, 0xF, 0xF, false);
    x = t < x ? t : x;
    t = __builtin_amdgcn_update_dpp(INF, x, 0x141, 0xF, 0xF, false);
    x = t < x ? t : x;
    t = __builtin_amdgcn_update_dpp(INF, x, 0x140, 0xF, 0xF, false);
    x = t < x ? t : x;
    t = __builtin_amdgcn_update_dpp(INF, x, 0x142, 0xF, 0xF, false);
    x = t < x ? t : x;
    t = __builtin_amdgcn_update_dpp(INF, x, 0x143, 0xF, 0xF, false);
    x = t < x ? t : x;
    return x;
}

// ============================ FPS =============================
// One block per (b,t) frame, 512 threads (8 waves), 16 points/thread held as
// 8 f32x2 pairs (packed v_pk_* update math; contract(off) keeps rn mul/add
// bit-exact vs reference, sum order ((x+y)+z)). ONE barrier per iteration:
// DPP wave-max + DPP wave-min-index, one u64 atomicMax per wave into a
// 3-deep ring (reset/read separated by a barrier -> race-free).
// key = (d2bits<<32)|(8191-idx): argmax with lowest-index tie-break
// (d2>=0 so f32 bits are order-monotone; matches jnp.argmax semantics).
__global__ __launch_bounds__(512)
void fps_kernel(const float* __restrict__ pts,
                float* __restrict__ out_xyz)
{
#pragma clang fp contract(off)
    const int bt  = blockIdx.x;        // b*4 + t0
    const int tid = threadIdx.x;
    const float* frame = pts + (size_t)bt * NPTS * 6;

    __shared__ float4 p4[NPTS];        // 128 KB coords copy
    __shared__ u64 ring[3];

    f32x2 x2[8], y2[8], z2[8], dd2[8];
#pragma unroll
    for (int j = 0; j < 16; ++j) {
        int n = j * 512 + tid;
        float x = frame[n*6+0], y = frame[n*6+1], z = frame[n*6+2];
        x2[j >> 1][j & 1] = x;
        y2[j >> 1][j & 1] = y;
        z2[j >> 1][j & 1] = z;
        dd2[j >> 1][j & 1] = 3.4028234663852886e38f;
        p4[n] = make_float4(x, y, z, 0.0f);
    }
    if (tid < 3) ring[tid] = 0;
    if (tid == 0) {                    // selection 0 = point 0
        float* ow = out_xyz + (size_t)bt * NS * 3;
        ow[0] = x2[0][0]; ow[1] = y2[0][0]; ow[2] = z2[0][0];
    }
    __syncthreads();
    float sx = p4[0].x, sy = p4[0].y, sz = p4[0].z;

    int r = 1;                         // ring slot for iteration i
    for (int i = 1; i < NS; ++i) {
        // packed update vs previous selection, track local max
        f32x2 sxv = {sx, sx}, syv = {sy, sy}, szv = {sz, sz};
        f32x2 m2 = {0.0f, 0.0f};
#pragma unroll
        for (int q = 0; q < 8; ++q) {
            f32x2 dx = x2[q] - sxv;
            f32x2 dy = y2[q] - syv;
            f32x2 dz = z2[q] - szv;
            f32x2 dd = (dx*dx + dy*dy) + dz*dz;
            f32x2 nd;
            nd[0] = fminf(dd2[q][0], dd[0]);
            nd[1] = fminf(dd2[q][1], dd[1]);
            dd2[q] = nd;
            m2[0] = fmaxf(m2[0], nd[0]);
            m2[1] = fmaxf(m2[1], nd[1]);
        }
        float mloc = fmaxf(m2[0], m2[1]);
        // lowest local index holding mloc (descending pass -> first match)
        int bestn = 0;
#pragma unroll
        for (int j = 15; j >= 0; --j)
            bestn = (dd2[j >> 1][j & 1] == mloc) ? (j * 512 + tid) : bestn;
        // wave reduce: max value, then min index among value-ties
        float wM = wave_max_f32_dpp(mloc);
        float M = __int_as_float(__builtin_amdgcn_readlane(__float_as_int(wM), 63));
        int cand = (mloc == M) ? bestn : 0x7FFFFFFF;
        int wI = wave_min_i32_dpp(cand);
        int idxm = __builtin_amdgcn_readlane(wI, 63);
        if ((tid & 63) == 0) {
            u64 key = ((u64)__float_as_uint(M) << 32) | (unsigned)(8191 - idxm);
            atomicMax(&ring[r], key);
        }
        int rn = r + 1; if (rn == 3) rn = 0;
        if (tid == 0) ring[rn] = 0;    // reset future slot (read 2 iters away)
        __syncthreads();
        u64 k = ring[r];
        int idx = 8191 - (int)(k & 0xFFFFFFFFu);
        float4 c = p4[idx];            // broadcast ds_read_b128
        sx = c.x; sy = c.y; sz = c.z;
        if (tid == 0) {
            float* ow = out_xyz + ((size_t)bt * NS + i) * 3;
            ow[0] = sx; ow[1] = sy; ow[2] = sz;
        }
        r = rn;
    }
}

// ============================ KNN =============================
// 1 wave (64 threads) per block, one anchor per lane. Per lane, in LDS
// columns (interleaved, stride 64 u64s): rows 0..31 = sorted main top-32,
// rows 32..63 = append buffer, row 64 = trash. Fast path is branchless:
// key = (d2bits<<32|idx); if key<rk append (losers write to trash row).
// Compaction (wave-uniform, lane-parallel): bitonic-sort buffer, one
// bitonic merge pass vs main keeping mins, 5 passes to re-sort, rk refresh.
// Exactness: rk lags (lazy), but key>=rk implies >=32 compacted keys are
// smaller -> safe to drop. Set/tie semantics identical to jax top_k
// (lexicographic (d2,idx)); downstream max-pool is order-insensitive.
__device__ __forceinline__ void knn_compact(u64* st, int lane, int& cnt, u64& rk)
{
    for (int e = 0; e < 32; ++e)
        if (e >= cnt) st[(e + 32) * 64 + lane] = ~0ull;
    for (int k = 2; k <= 32; k <<= 1)
        for (int j = k >> 1; j > 0; j >>= 1)
            for (int i = 0; i < 32; ++i) {
                int l = i ^ j;
                if (l > i) {
                    u64 a = st[(i + 32) * 64 + lane];
                    u64 b = st[(l + 32) * 64 + lane];
                    bool asc = ((i & k) == 0);
                    if ((a > b) == asc) {
                        st[(i + 32) * 64 + lane] = b;
                        st[(l + 32) * 64 + lane] = a;
                    }
                }
            }
    for (int i = 0; i < 32; ++i) {
        u64 a = st[i * 64 + lane];
        u64 b = st[(63 - i) * 64 + lane];
        if (b < a) st[i * 64 + lane] = b;
    }
    for (int j = 16; j > 0; j >>= 1)
        for (int i = 0; i < 32; ++i) {
            int l = i ^ j;
            if (l > i) {
                u64 a = st[i * 64 + lane];
                u64 b = st[l * 64 + lane];
                if (a > b) {
                    st[i * 64 + lane] = b;
                    st[l * 64 + lane] = a;
                }
            }
        }
    rk = st[31 * 64 + lane];
    cnt = 0;
}

__global__ __launch_bounds__(64)
void knn_kernel(const float* __restrict__ pts,
                const float* __restrict__ anchors,
                unsigned short* __restrict__ knn_out)
{
    const int blk  = blockIdx.x;       // 8bt * 3di * 32 sblk
    const int bt   = blk / 96;
    const int r    = blk % 96;
    const int di   = r / 32;
    const int sblk = r % 32;
    const int b = bt >> 2, t0 = bt & 3;
    int lnb = t0 + di - 1; lnb = lnb < 0 ? 0 : (lnb > 3 ? 3 : lnb);
    const float* nb = pts + (size_t)(b * 4 + lnb) * NPTS * 6;
    const int lane = threadIdx.x;
    const int s    = sblk * 64 + lane;

    const float* ap = anchors + ((size_t)bt * NS + s) * 3;
    float ax = ap[0], ay = ap[1], az = ap[2];

    __shared__ u64 st[65 * 64];        // 33.25 KB
    __shared__ float4 tile[512];       // 8 KB

    for (int e = 0; e < 64; ++e) st[e * 64 + lane] = ~0ull;
    u64 rk = ~0ull;
    int cnt = 0;

    for (int tb = 0; tb < NPTS; tb += 512) {
        __syncthreads();
#pragma unroll
        for (int q = 0; q < 8; ++q) {
            int c = q * 64 + lane;
            int n = tb + c;
            tile[c] = make_float4(nb[n*6+0], nb[n*6+1], nb[n*6+2], 0.0f);
        }
        __syncthreads();
        for (int c0 = 0; c0 < 512; c0 += 8) {
#pragma unroll
            for (int j = 0; j < 8; ++j) {
                float4 qv = tile[c0 + j];
                float dx = __fsub_rn(ax, qv.x);
                float dy = __fsub_rn(ay, qv.y);
                float dz = __fsub_rn(az, qv.z);
                float d2 = __fadd_rn(__fadd_rn(__fmul_rn(dx,dx), __fmul_rn(dy,dy)),
                                     __fmul_rn(dz,dz));
                u64 key = ((u64)__float_as_uint(d2) << 32)
                        | (unsigned)(tb + c0 + j);
                bool p = key < rk;
                int row = p ? (32 + cnt) : 64;
                st[row * 64 + lane] = key;
                cnt += p ? 1 : 0;
            }
            if (__any(cnt >= 24)) knn_compact(st, lane, cnt, rk);
        }
    }
    knn_compact(st, lane, cnt, rk);

    unsigned short* op = knn_out + (((size_t)bt * 3 + di) * NS + s) * KNNK;
#pragma unroll
    for (int e = 0; e < 32; ++e)
        op[e] = (unsigned short)(st[e * 64 + lane] & 0xFFFFull);
}

// ============================ MLP =============================
// Block = 2 anchors x 128 channels. h1 staged in LDS [2][64][36] (stride 36:
// bank-clean, 16B aligned rows for ds_read_b128 along k). relu/max commute.
__global__ __launch_bounds__(256)
void mlp_kernel(const float* __restrict__ pts,
                const float* __restrict__ anchors,
                const unsigned short* __restrict__ knn,
                const float* __restrict__ Wd,
                const float* __restrict__ Wm,
                float* __restrict__ out_feats)
{
    const int blk   = blockIdx.x;
    const int bt    = blk >> 10;
    const int spair = blk & 1023;
    const int b = bt >> 2, t0 = bt & 3;
    const int tid = threadIdx.x;
    const int a   = tid >> 7;
    const int p   = tid & 127;
    const int s   = spair * 2 + a;

    __shared__ float WmT[64 * 128];
    __shared__ float Wds[256];
    __shared__ float h1[2][64][36];
    __shared__ float d4s[2][32][4];

    for (int i = tid; i < 8192; i += 256) {
        int pp = i >> 6, oo = i & 63;
        WmT[oo * 128 + pp] = Wm[i];
    }
    Wds[tid & 255] = Wd[tid & 255];

    float fsum = 0.0f;

    for (int dd = 0; dd < 3; ++dd) {
        __syncthreads();
        if (tid < 64) {
            int sa = tid >> 5, k = tid & 31;
            int ss = spair * 2 + sa;
            int lnb = t0 + dd - 1; lnb = lnb < 0 ? 0 : (lnb > 3 ? 3 : lnb);
            const float* nbf = pts + (size_t)(b*4 + lnb) * NPTS * 6;
            const float* ap = anchors + ((size_t)bt * NS + ss) * 3;
            int idx = knn[(((size_t)bt*3 + dd) * NS + ss) * KNNK + k];
            d4s[sa][k][0] = nbf[idx*6+0] - ap[0];
            d4s[sa][k][1] = nbf[idx*6+1] - ap[1];
            d4s[sa][k][2] = nbf[idx*6+2] - ap[2];
            d4s[sa][k][3] = (float)(dd - 1);
        }
        __syncthreads();
        {
            int k  = tid & 31;
            int oq = (tid >> 5) & 3;
            float4 dv = *(const float4*)&d4s[a][k][0];
#pragma unroll
            for (int ii = 0; ii < 16; ++ii) {
                int o = oq * 16 + ii;
                float4 w = *(const float4*)&Wds[o * 4];
                float h = fmaf(dv.x, w.x, fmaf(dv.y, w.y, fmaf(dv.z, w.z, dv.w * w.w)));
                h1[a][o][k] = fmaxf(h, 0.0f);
            }
        }
        __syncthreads();
        float acc[32];
#pragma unroll
        for (int kk = 0; kk < 32; ++kk) acc[kk] = 0.0f;
        for (int o = 0; o < 64; ++o) {
            float wmv = WmT[o * 128 + p];
            const float4* hp = (const float4*)&h1[a][o][0];
#pragma unroll
            for (int kk = 0; kk < 8; ++kk) {
                float4 hv = hp[kk];
                acc[kk*4+0] = fmaf(wmv, hv.x, acc[kk*4+0]);
                acc[kk*4+1] = fmaf(wmv, hv.y, acc[kk*4+1]);
                acc[kk*4+2] = fmaf(wmv, hv.z, acc[kk*4+2]);
                acc[kk*4+3] = fmaf(wmv, hv.w, acc[kk*4+3]);
            }
        }
        float mx = acc[0];
#pragma unroll
        for (int kk = 1; kk < 32; ++kk) mx = fmaxf(mx, acc[kk]);
        fsum += fmaxf(mx, 0.0f);
    }
    out_feats[((size_t)bt * 128 + p) * NS + s] = fsum;
}

// ========================== launcher ==========================
extern "C" void kernel_launch(void* const* d_in, const int* in_sizes, int n_in,
                              void* d_out, int out_size, void* d_ws, size_t ws_size,
                              hipStream_t stream)
{
    const float* pts = (const float*)d_in[0];   // [2,4,8192,6]
    const float* Wd  = (const float*)d_in[1];   // [64,4]
    const float* Wm  = (const float*)d_in[2];   // [128,64]

    float* out_xyz   = (float*)d_out;                 // [2,4,2048,3] == anchors
    float* out_feats = out_xyz + 8 * NS * 3;          // [2,4,128,2048]

    unsigned short* knn = (unsigned short*)d_ws;      // 8*3*2048*32 u16

    fps_kernel<<<8, 512, 0, stream>>>(pts, out_xyz);
    knn_kernel<<<8 * 3 * 32, 64, 0, stream>>>(pts, out_xyz, knn);
    mlp_kernel<<<8 * (NS / 2), 256, 0, stream>>>(pts, out_xyz, knn, Wd, Wm, out_feats);
}